// Round 1
// baseline (1068.467 us; speedup 1.0000x reference)
//
#include <hip/hip_runtime.h>
#include <hip/hip_bf16.h>
#include <stdint.h>

#define T_TOK 8192
#define H_DIM 1024
#define F_DIM 4096
#define NEXP  8
#define CAP        17408   // 16384 + 8*128 worst-case aligned padding
#define CAP_TILES  136     // CAP/128

typedef __attribute__((ext_vector_type(8))) short bf16x8;
typedef __attribute__((ext_vector_type(4))) float f32x4;

#define AS1 __attribute__((address_space(1)))
#define AS3 __attribute__((address_space(3)))

__device__ __forceinline__ void gload_lds16(const void* g, void* l) {
  __builtin_amdgcn_global_load_lds((const AS1 void*)g, (AS3 void*)l, 16, 0, 0);
}

struct TK { int i0, i1; float w0, w1; };

// ---------------- router: fp32 logits, softmax, top-2, renorm ----------------
__global__ __launch_bounds__(256) void router_kernel(
    const float* __restrict__ x, const float* __restrict__ gw,
    float* __restrict__ logits, int* __restrict__ counts, TK* __restrict__ tk)
{
  const int lane = threadIdx.x & 63;
  const int t = blockIdx.x * 4 + (threadIdx.x >> 6);
  const float* xp = x + (size_t)t * H_DIM;
  float xr[16];
#pragma unroll
  for (int i = 0; i < 16; ++i) xr[i] = xp[lane + i * 64];
  float lg[NEXP];
#pragma unroll
  for (int e = 0; e < NEXP; ++e) {
    const float* gp = gw + e * H_DIM;
    float acc = 0.f;
#pragma unroll
    for (int i = 0; i < 16; ++i) acc += xr[i] * gp[lane + i * 64];
#pragma unroll
    for (int s = 32; s > 0; s >>= 1) acc += __shfl_xor(acc, s, 64);
    lg[e] = acc;
  }
  if (lane < NEXP) logits[(size_t)t * NEXP + lane] = lg[lane];
  if (lane == 0) {
    int i0 = 0; float m0 = lg[0];
#pragma unroll
    for (int e = 1; e < NEXP; ++e) if (lg[e] > m0) { m0 = lg[e]; i0 = e; }
    int i1 = -1; float m1 = -1e30f;
#pragma unroll
    for (int e = 0; e < NEXP; ++e) if (e != i0 && lg[e] > m1) { m1 = lg[e]; i1 = e; }
    float r = expf(m1 - m0);            // top-2 renormalized softmax
    float w0 = 1.f / (1.f + r);
    float w1 = r / (1.f + r);
    TK v; v.i0 = i0; v.i1 = i1; v.w0 = w0; v.w1 = w1;
    tk[t] = v;
    atomicAdd(&counts[i0], 1);
    atomicAdd(&counts[i1], 1);
  }
}

// ---------------- scan: aligned segment offsets + tile->expert map ----------
__global__ void scan_kernel(const int* __restrict__ counts, int* __restrict__ offs,
                            int* __restrict__ cursor, int* __restrict__ tile_expert)
{
  if (threadIdx.x == 0 && blockIdx.x == 0) {
    int o = 0;
    for (int e = 0; e < NEXP; ++e) {
      offs[e] = o; cursor[e] = o;
      o += (counts[e] + 127) & ~127;
    }
    offs[NEXP] = o;
    for (int ti = 0; ti < CAP_TILES; ++ti) {
      int row = ti * 128;
      int e = NEXP - 1;
      for (int k = 0; k < NEXP; ++k)
        if (row >= offs[k] && row < offs[k + 1]) { e = k; break; }
      tile_expert[ti] = e;   // tail tiles (row >= offs[8]) keep e=7; their weights are 0
    }
  }
}

// ---------------- scatter: token -> slot in expert-sorted list --------------
__global__ __launch_bounds__(256) void scatter_kernel(
    const TK* __restrict__ tk, int* __restrict__ cursor,
    int* __restrict__ pair_tok, float* __restrict__ pair_w)
{
  int t = blockIdx.x * 256 + threadIdx.x;
  if (t >= T_TOK) return;
  TK v = tk[t];
  int p0 = atomicAdd(&cursor[v.i0], 1);
  pair_tok[p0] = t; pair_w[p0] = v.w0;
  int p1 = atomicAdd(&cursor[v.i1], 1);
  pair_tok[p1] = t; pair_w[p1] = v.w1;
}

// ---------------- gather: x fp32 rows -> bf16 xg (expert-sorted) ------------
union Pack8 { __hip_bfloat16 o[8]; uint4 u; };

__global__ __launch_bounds__(256) void gather_kernel(
    const float* __restrict__ x, const int* __restrict__ pair_tok,
    __hip_bfloat16* __restrict__ xg)
{
  int idx = blockIdx.x * 256 + threadIdx.x;   // CAP*128 threads
  int row = idx >> 7;
  int c8  = (idx & 127) << 3;
  int tok = pair_tok[row];                    // pad rows: tok=0, harmless
  const float4* src = reinterpret_cast<const float4*>(x + (size_t)tok * H_DIM + c8);
  float4 a = src[0], b = src[1];
  Pack8 pk;
  pk.o[0] = __float2bfloat16(a.x); pk.o[1] = __float2bfloat16(a.y);
  pk.o[2] = __float2bfloat16(a.z); pk.o[3] = __float2bfloat16(a.w);
  pk.o[4] = __float2bfloat16(b.x); pk.o[5] = __float2bfloat16(b.y);
  pk.o[6] = __float2bfloat16(b.z); pk.o[7] = __float2bfloat16(b.w);
  *reinterpret_cast<uint4*>(xg + (size_t)row * H_DIM + c8) = pk.u;
}

// ---------------- weight convert fp32 -> bf16 -------------------------------
__global__ __launch_bounds__(256) void convert_kernel(
    const float* __restrict__ src, __hip_bfloat16* __restrict__ dst, long long n)
{
  long long i = ((long long)blockIdx.x * 256 + threadIdx.x) * 8;
  if (i >= n) return;
  float4 a = *reinterpret_cast<const float4*>(src + i);
  float4 b = *reinterpret_cast<const float4*>(src + i + 4);
  Pack8 pk;
  pk.o[0] = __float2bfloat16(a.x); pk.o[1] = __float2bfloat16(a.y);
  pk.o[2] = __float2bfloat16(a.z); pk.o[3] = __float2bfloat16(a.w);
  pk.o[4] = __float2bfloat16(b.x); pk.o[5] = __float2bfloat16(b.y);
  pk.o[6] = __float2bfloat16(b.z); pk.o[7] = __float2bfloat16(b.w);
  *reinterpret_cast<uint4*>(dst + i) = pk.u;
}

// ---------------- GEMM1: h = silu(Xg @ w1[e]^T) * (Xg @ w3[e]^T) ------------
// 128x128 tile, BK=32, 4 waves (2x2), each wave 64x64 (4x4 frags of 16x16x32).
__global__ __launch_bounds__(256, 2) void gemm1_kernel(
    const __hip_bfloat16* __restrict__ xg,
    const __hip_bfloat16* __restrict__ w1b,
    const __hip_bfloat16* __restrict__ w3b,
    const int* __restrict__ tile_expert,
    __hip_bfloat16* __restrict__ h)
{
  __shared__ __hip_bfloat16 sA[128 * 32], sB1[128 * 32], sB3[128 * 32];
  const int tm = blockIdx.x;          // row tile 0..135
  const int tf = blockIdx.y;          // f tile 0..31
  const int e  = tile_expert[tm];
  const int tid = threadIdx.x;

  const __hip_bfloat16* A  = xg  + (size_t)tm * 128 * H_DIM;
  const __hip_bfloat16* B1 = w1b + (size_t)e * F_DIM * H_DIM + (size_t)tf * 128 * H_DIM;
  const __hip_bfloat16* B3 = w3b + (size_t)e * F_DIM * H_DIM + (size_t)tf * 128 * H_DIM;

  const int r   = tid >> 2;           // 0..63 (staging row)
  const int kc  = (tid & 3) * 8;      // staging k offset (elems)
  const int lo  = tid * 8;            // linear LDS elem offset for this thread

  f32x4 acc1[4][4] = {};
  f32x4 acc3[4][4] = {};

  const int wv = tid >> 6, lane = tid & 63;
  const int wr = wv >> 1, wc = wv & 1;
  const int l16 = lane & 15, lk = lane >> 4;

  for (int kt = 0; kt < H_DIM / 32; ++kt) {
    __syncthreads();
    const int gk = kt * 32 + kc;
    gload_lds16(A  + (size_t)r * H_DIM + gk,          &sA [lo]);
    gload_lds16(A  + (size_t)(r + 64) * H_DIM + gk,   &sA [2048 + lo]);
    gload_lds16(B1 + (size_t)r * H_DIM + gk,          &sB1[lo]);
    gload_lds16(B1 + (size_t)(r + 64) * H_DIM + gk,   &sB1[2048 + lo]);
    gload_lds16(B3 + (size_t)r * H_DIM + gk,          &sB3[lo]);
    gload_lds16(B3 + (size_t)(r + 64) * H_DIM + gk,   &sB3[2048 + lo]);
    __syncthreads();

    bf16x8 af[4], b1f[4], b3f[4];
#pragma unroll
    for (int m = 0; m < 4; ++m)
      af[m] = *reinterpret_cast<const bf16x8*>(&sA[(wr * 64 + m * 16 + l16) * 32 + lk * 8]);
#pragma unroll
    for (int n = 0; n < 4; ++n) {
      b1f[n] = *reinterpret_cast<const bf16x8*>(&sB1[(wc * 64 + n * 16 + l16) * 32 + lk * 8]);
      b3f[n] = *reinterpret_cast<const bf16x8*>(&sB3[(wc * 64 + n * 16 + l16) * 32 + lk * 8]);
    }
#pragma unroll
    for (int m = 0; m < 4; ++m)
#pragma unroll
      for (int n = 0; n < 4; ++n) {
        acc1[m][n] = __builtin_amdgcn_mfma_f32_16x16x32_bf16(af[m], b1f[n], acc1[m][n], 0, 0, 0);
        acc3[m][n] = __builtin_amdgcn_mfma_f32_16x16x32_bf16(af[m], b3f[n], acc3[m][n], 0, 0, 0);
      }
  }

  __hip_bfloat16* hp = h + (size_t)tm * 128 * F_DIM + (size_t)tf * 128;
#pragma unroll
  for (int m = 0; m < 4; ++m)
#pragma unroll
    for (int n = 0; n < 4; ++n)
#pragma unroll
      for (int j = 0; j < 4; ++j) {
        int row = wr * 64 + m * 16 + lk * 4 + j;   // C/D: col=lane&15, row=(lane>>4)*4+j
        int col = wc * 64 + n * 16 + l16;
        float c1 = acc1[m][n][j];
        float c3 = acc3[m][n][j];
        float s  = c1 / (1.f + expf(-c1));
        hp[(size_t)row * F_DIM + col] = __float2bfloat16(s * c3);
      }
}

// ---------------- GEMM2: out[tok] += w * (h @ w2[e]^T) ----------------------
__global__ __launch_bounds__(256) void gemm2_kernel(
    const __hip_bfloat16* __restrict__ h,
    const __hip_bfloat16* __restrict__ w2b,
    const int* __restrict__ tile_expert,
    const int* __restrict__ pair_tok,
    const float* __restrict__ pair_w,
    float* __restrict__ out)
{
  __shared__ __hip_bfloat16 sA[128 * 32], sB[128 * 32];
  const int tm = blockIdx.x;          // row tile 0..135
  const int tn = blockIdx.y;          // H tile 0..7
  const int e  = tile_expert[tm];
  const int tid = threadIdx.x;

  const __hip_bfloat16* A = h   + (size_t)tm * 128 * F_DIM;
  const __hip_bfloat16* B = w2b + (size_t)e * H_DIM * F_DIM + (size_t)tn * 128 * F_DIM;

  const int r  = tid >> 2;
  const int kc = (tid & 3) * 8;
  const int lo = tid * 8;

  f32x4 acc[4][4] = {};
  const int wv = tid >> 6, lane = tid & 63;
  const int wr = wv >> 1, wc = wv & 1;
  const int l16 = lane & 15, lk = lane >> 4;

  for (int kt = 0; kt < F_DIM / 32; ++kt) {
    __syncthreads();
    const int gk = kt * 32 + kc;
    gload_lds16(A + (size_t)r * F_DIM + gk,          &sA[lo]);
    gload_lds16(A + (size_t)(r + 64) * F_DIM + gk,   &sA[2048 + lo]);
    gload_lds16(B + (size_t)r * F_DIM + gk,          &sB[lo]);
    gload_lds16(B + (size_t)(r + 64) * F_DIM + gk,   &sB[2048 + lo]);
    __syncthreads();

    bf16x8 af[4], bf[4];
#pragma unroll
    for (int m = 0; m < 4; ++m)
      af[m] = *reinterpret_cast<const bf16x8*>(&sA[(wr * 64 + m * 16 + l16) * 32 + lk * 8]);
#pragma unroll
    for (int n = 0; n < 4; ++n)
      bf[n] = *reinterpret_cast<const bf16x8*>(&sB[(wc * 64 + n * 16 + l16) * 32 + lk * 8]);
#pragma unroll
    for (int m = 0; m < 4; ++m)
#pragma unroll
      for (int n = 0; n < 4; ++n)
        acc[m][n] = __builtin_amdgcn_mfma_f32_16x16x32_bf16(af[m], bf[n], acc[m][n], 0, 0, 0);
  }

#pragma unroll
  for (int m = 0; m < 4; ++m)
#pragma unroll
    for (int j = 0; j < 4; ++j) {
      int rowg = tm * 128 + wr * 64 + m * 16 + lk * 4 + j;
      float w = pair_w[rowg];
      if (w != 0.f) {
        int tok = pair_tok[rowg];
        float* op = out + (size_t)tok * H_DIM + tn * 128 + wc * 64;
#pragma unroll
        for (int n = 0; n < 4; ++n)
          atomicAdd(op + n * 16 + l16, w * acc[m][n][j]);
      }
    }
}

// ---------------- workspace layout ------------------------------------------
#define WS_COUNTS   0
#define WS_CURSOR   32
#define WS_OFFS     64
#define WS_TILEEXP  128
#define WS_TK       1024
#define WS_PAIRTOK  132096
#define WS_PAIRW    201728
#define WS_ZERO_BYTES 271360
#define WS_XG       271872ll
#define WS_W1       (WS_XG + 35651584ll)
#define WS_W3       (WS_W1 + 67108864ll)
#define WS_W2       (WS_W3 + 67108864ll)
#define WS_H        (WS_W2 + 67108864ll)

extern "C" void kernel_launch(void* const* d_in, const int* in_sizes, int n_in,
                              void* d_out, int out_size, void* d_ws, size_t ws_size,
                              hipStream_t stream) {
  const float* x  = (const float*)d_in[0];
  const float* gw = (const float*)d_in[1];
  const float* w1 = (const float*)d_in[2];
  const float* w3 = (const float*)d_in[3];
  const float* w2 = (const float*)d_in[4];
  float* out    = (float*)d_out;
  float* logits = out + (size_t)T_TOK * H_DIM;

  char* ws = (char*)d_ws;
  int*   counts   = (int*)(ws + WS_COUNTS);
  int*   cursor   = (int*)(ws + WS_CURSOR);
  int*   offs     = (int*)(ws + WS_OFFS);
  int*   tile_exp = (int*)(ws + WS_TILEEXP);
  TK*    tk       = (TK*)(ws + WS_TK);
  int*   pair_tok = (int*)(ws + WS_PAIRTOK);
  float* pair_w   = (float*)(ws + WS_PAIRW);
  __hip_bfloat16* xg  = (__hip_bfloat16*)(ws + WS_XG);
  __hip_bfloat16* w1b = (__hip_bfloat16*)(ws + WS_W1);
  __hip_bfloat16* w3b = (__hip_bfloat16*)(ws + WS_W3);
  __hip_bfloat16* w2b = (__hip_bfloat16*)(ws + WS_W2);
  __hip_bfloat16* hbuf = (__hip_bfloat16*)(ws + WS_H);

  hipMemsetAsync(d_ws, 0, WS_ZERO_BYTES, stream);
  hipMemsetAsync(d_out, 0, (size_t)T_TOK * H_DIM * sizeof(float), stream);

  const long long nW = (long long)NEXP * F_DIM * H_DIM;   // 33,554,432
  convert_kernel<<<16384, 256, 0, stream>>>(w1, w1b, nW);
  convert_kernel<<<16384, 256, 0, stream>>>(w3, w3b, nW);
  convert_kernel<<<16384, 256, 0, stream>>>(w2, w2b, nW);

  router_kernel<<<T_TOK / 4, 256, 0, stream>>>(x, gw, logits, counts, tk);
  scan_kernel<<<1, 64, 0, stream>>>(counts, offs, cursor, tile_exp);
  scatter_kernel<<<T_TOK / 256, 256, 0, stream>>>(tk, cursor, pair_tok, pair_w);
  gather_kernel<<<(CAP * 128) / 256, 256, 0, stream>>>(x, pair_tok, xg);

  gemm1_kernel<<<dim3(CAP_TILES, F_DIM / 128), 256, 0, stream>>>(
      xg, w1b, w3b, tile_exp, hbuf);
  gemm2_kernel<<<dim3(CAP_TILES, H_DIM / 128), 256, 0, stream>>>(
      hbuf, w2b, tile_exp, pair_tok, pair_w, out);
}

// Round 2
// 1010.888 us; speedup vs baseline: 1.0570x; 1.0570x over previous
//
#include <hip/hip_runtime.h>
#include <hip/hip_bf16.h>
#include <stdint.h>

#define T_TOK 8192
#define H_DIM 1024
#define F_DIM 4096
#define NEXP  8
#define CAP        17408   // 16384 + 8*128 worst-case aligned padding
#define CAP_TILES  136     // CAP/128

typedef __attribute__((ext_vector_type(8))) short bf16x8;
typedef __attribute__((ext_vector_type(4))) float f32x4;

#define AS1 __attribute__((address_space(1)))
#define AS3 __attribute__((address_space(3)))

__device__ __forceinline__ void gload_lds16(const void* g, void* l) {
  __builtin_amdgcn_global_load_lds((const AS1 void*)g, (AS3 void*)l, 16, 0, 0);
}

struct TK { int i0, i1; float w0, w1; };

// ---------------- router: fp32 logits, softmax, top-2, renorm ----------------
__global__ __launch_bounds__(256) void router_kernel(
    const float* __restrict__ x, const float* __restrict__ gw,
    float* __restrict__ logits, int* __restrict__ counts, TK* __restrict__ tk)
{
  const int lane = threadIdx.x & 63;
  const int t = blockIdx.x * 4 + (threadIdx.x >> 6);
  const float* xp = x + (size_t)t * H_DIM;
  float xr[16];
#pragma unroll
  for (int i = 0; i < 16; ++i) xr[i] = xp[lane + i * 64];
  float lg[NEXP];
#pragma unroll
  for (int e = 0; e < NEXP; ++e) {
    const float* gp = gw + e * H_DIM;
    float acc = 0.f;
#pragma unroll
    for (int i = 0; i < 16; ++i) acc += xr[i] * gp[lane + i * 64];
#pragma unroll
    for (int s = 32; s > 0; s >>= 1) acc += __shfl_xor(acc, s, 64);
    lg[e] = acc;
  }
  if (lane < NEXP) logits[(size_t)t * NEXP + lane] = lg[lane];
  if (lane == 0) {
    int i0 = 0; float m0 = lg[0];
#pragma unroll
    for (int e = 1; e < NEXP; ++e) if (lg[e] > m0) { m0 = lg[e]; i0 = e; }
    int i1 = -1; float m1 = -1e30f;
#pragma unroll
    for (int e = 0; e < NEXP; ++e) if (e != i0 && lg[e] > m1) { m1 = lg[e]; i1 = e; }
    float r = expf(m1 - m0);            // top-2 renormalized softmax
    float w0 = 1.f / (1.f + r);
    float w1 = r / (1.f + r);
    TK v; v.i0 = i0; v.i1 = i1; v.w0 = w0; v.w1 = w1;
    tk[t] = v;
    atomicAdd(&counts[i0], 1);
    atomicAdd(&counts[i1], 1);
  }
}

// ---------------- scan: aligned segment offsets + tile->expert map ----------
__global__ __launch_bounds__(256) void scan_kernel(
    const int* __restrict__ counts, int* __restrict__ offs,
    int* __restrict__ cursor, int* __restrict__ tile_expert)
{
  __shared__ int so[NEXP + 1];
  const int tid = threadIdx.x;
  if (tid == 0) {
    int o = 0;
    for (int e = 0; e < NEXP; ++e) {
      so[e] = o; offs[e] = o; cursor[e] = o;
      o += (counts[e] + 127) & ~127;
    }
    so[NEXP] = o; offs[NEXP] = o;
  }
  __syncthreads();
  for (int ti = tid; ti < CAP_TILES; ti += 256) {
    int row = ti * 128;
    int e = NEXP - 1;
#pragma unroll
    for (int k = 0; k < NEXP; ++k)
      if (row >= so[k] && row < so[k + 1]) { e = k; break; }
    tile_expert[ti] = e;   // tail tiles keep e=7; their weights are 0
  }
}

// ---------------- scatter: token -> slot in expert-sorted list --------------
__global__ __launch_bounds__(256) void scatter_kernel(
    const TK* __restrict__ tk, int* __restrict__ cursor,
    int* __restrict__ pair_tok, float* __restrict__ pair_w,
    int2* __restrict__ inv)
{
  int t = blockIdx.x * 256 + threadIdx.x;
  if (t >= T_TOK) return;
  TK v = tk[t];
  int p0 = atomicAdd(&cursor[v.i0], 1);
  pair_tok[p0] = t; pair_w[p0] = v.w0;
  int p1 = atomicAdd(&cursor[v.i1], 1);
  pair_tok[p1] = t; pair_w[p1] = v.w1;
  inv[t] = make_int2(p0, p1);
}

// ---------------- gather: x fp32 rows -> bf16 xg (expert-sorted) ------------
union Pack8 { __hip_bfloat16 o[8]; uint4 u; };

__global__ __launch_bounds__(256) void gather_kernel(
    const float* __restrict__ x, const int* __restrict__ pair_tok,
    __hip_bfloat16* __restrict__ xg)
{
  int idx = blockIdx.x * 256 + threadIdx.x;   // CAP*128 threads
  int row = idx >> 7;
  int c8  = (idx & 127) << 3;
  int tok = pair_tok[row];                    // pad rows: tok=0, harmless
  const float4* src = reinterpret_cast<const float4*>(x + (size_t)tok * H_DIM + c8);
  float4 a = src[0], b = src[1];
  Pack8 pk;
  pk.o[0] = __float2bfloat16(a.x); pk.o[1] = __float2bfloat16(a.y);
  pk.o[2] = __float2bfloat16(a.z); pk.o[3] = __float2bfloat16(a.w);
  pk.o[4] = __float2bfloat16(b.x); pk.o[5] = __float2bfloat16(b.y);
  pk.o[6] = __float2bfloat16(b.z); pk.o[7] = __float2bfloat16(b.w);
  *reinterpret_cast<uint4*>(xg + (size_t)row * H_DIM + c8) = pk.u;
}

// ---------------- weight convert fp32 -> bf16 -------------------------------
__global__ __launch_bounds__(256) void convert_kernel(
    const float* __restrict__ src, __hip_bfloat16* __restrict__ dst, long long n)
{
  long long i = ((long long)blockIdx.x * 256 + threadIdx.x) * 8;
  if (i >= n) return;
  float4 a = *reinterpret_cast<const float4*>(src + i);
  float4 b = *reinterpret_cast<const float4*>(src + i + 4);
  Pack8 pk;
  pk.o[0] = __float2bfloat16(a.x); pk.o[1] = __float2bfloat16(a.y);
  pk.o[2] = __float2bfloat16(a.z); pk.o[3] = __float2bfloat16(a.w);
  pk.o[4] = __float2bfloat16(b.x); pk.o[5] = __float2bfloat16(b.y);
  pk.o[6] = __float2bfloat16(b.z); pk.o[7] = __float2bfloat16(b.w);
  *reinterpret_cast<uint4*>(dst + i) = pk.u;
}

// ===== LDS tile layout: [128 rows][32 k] bf16, 64B rows, 4x 16B slots/row.
// XOR swizzle (T2, rule #21 both-sides): physical slot p at row r holds
// logical slot p ^ g(r), g(r) = (r>>1)&3.  Write side: linear global_load_lds
// dest + pre-swizzled GLOBAL source slot.  Read side: slot = lk ^ g(row).
// Verified: lanes 0-15 hit 8 distinct bank-starts covering 32 banks,
// 2 lanes/start = conflict-free (m136).

// ---------------- GEMM1: h = silu(Xg @ w1[e]^T) * (Xg @ w3[e]^T) ------------
__global__ __launch_bounds__(256, 2) void gemm1_kernel(
    const __hip_bfloat16* __restrict__ xg,
    const __hip_bfloat16* __restrict__ w1b,
    const __hip_bfloat16* __restrict__ w3b,
    const int* __restrict__ tile_expert,
    __hip_bfloat16* __restrict__ h)
{
  __shared__ __hip_bfloat16 sA[128 * 32], sB1[128 * 32], sB3[128 * 32];
  const int n_ = blockIdx.x;                    // 0..4351
  const int swz = (n_ & 7) * 544 + (n_ >> 3);   // bijective XCD swizzle (T1)
  const int tf = swz & 31;                      // f tile 0..31
  const int tm = swz >> 5;                      // row tile 0..135
  const int e  = tile_expert[tm];
  const int tid = threadIdx.x;

  const __hip_bfloat16* A  = xg  + (size_t)tm * 128 * H_DIM;
  const __hip_bfloat16* B1 = w1b + (size_t)e * F_DIM * H_DIM + (size_t)tf * 128 * H_DIM;
  const __hip_bfloat16* B3 = w3b + (size_t)e * F_DIM * H_DIM + (size_t)tf * 128 * H_DIM;

  const int r     = tid >> 2;                       // staging row 0..63
  const int s_src = (tid & 3) ^ ((r >> 1) & 3);     // pre-swizzled global slot
  const int kc    = s_src * 8;
  const int lo    = tid * 8;                        // linear LDS dest (16B/thread)

  f32x4 acc1[4][4] = {};
  f32x4 acc3[4][4] = {};

  const int wv = tid >> 6, lane = tid & 63;
  const int wr = wv >> 1, wc = wv & 1;
  const int l16 = lane & 15, lk = lane >> 4;
  const int rdk = (lk * 8) ^ (((l16 >> 1) & 3) * 8);  // swizzled read slot (elems)

  for (int kt = 0; kt < H_DIM / 32; ++kt) {
    __syncthreads();
    const int gk = kt * 32 + kc;
    gload_lds16(A  + (size_t)r * H_DIM + gk,          &sA [lo]);
    gload_lds16(A  + (size_t)(r + 64) * H_DIM + gk,   &sA [2048 + lo]);
    gload_lds16(B1 + (size_t)r * H_DIM + gk,          &sB1[lo]);
    gload_lds16(B1 + (size_t)(r + 64) * H_DIM + gk,   &sB1[2048 + lo]);
    gload_lds16(B3 + (size_t)r * H_DIM + gk,          &sB3[lo]);
    gload_lds16(B3 + (size_t)(r + 64) * H_DIM + gk,   &sB3[2048 + lo]);
    __syncthreads();

    bf16x8 af[4], b1f[4], b3f[4];
#pragma unroll
    for (int m = 0; m < 4; ++m)
      af[m] = *reinterpret_cast<const bf16x8*>(&sA[(wr * 64 + m * 16 + l16) * 32 + rdk]);
#pragma unroll
    for (int n = 0; n < 4; ++n) {
      b1f[n] = *reinterpret_cast<const bf16x8*>(&sB1[(wc * 64 + n * 16 + l16) * 32 + rdk]);
      b3f[n] = *reinterpret_cast<const bf16x8*>(&sB3[(wc * 64 + n * 16 + l16) * 32 + rdk]);
    }
#pragma unroll
    for (int m = 0; m < 4; ++m)
#pragma unroll
      for (int n = 0; n < 4; ++n) {
        acc1[m][n] = __builtin_amdgcn_mfma_f32_16x16x32_bf16(af[m], b1f[n], acc1[m][n], 0, 0, 0);
        acc3[m][n] = __builtin_amdgcn_mfma_f32_16x16x32_bf16(af[m], b3f[n], acc3[m][n], 0, 0, 0);
      }
  }

  __hip_bfloat16* hp = h + (size_t)tm * 128 * F_DIM + (size_t)tf * 128;
#pragma unroll
  for (int m = 0; m < 4; ++m)
#pragma unroll
    for (int n = 0; n < 4; ++n)
#pragma unroll
      for (int j = 0; j < 4; ++j) {
        int row = wr * 64 + m * 16 + lk * 4 + j;   // C/D: col=lane&15, row=(lane>>4)*4+j
        int col = wc * 64 + n * 16 + l16;
        float c1 = acc1[m][n][j];
        float c3 = acc3[m][n][j];
        float s  = c1 / (1.f + expf(-c1));
        hp[(size_t)row * F_DIM + col] = __float2bfloat16(s * c3);
      }
}

// ---------------- GEMM2: y[slot] = w[slot] * (h @ w2[e]^T)  (no atomics) ----
__global__ __launch_bounds__(256, 2) void gemm2_kernel(
    const __hip_bfloat16* __restrict__ h,
    const __hip_bfloat16* __restrict__ w2b,
    const int* __restrict__ tile_expert,
    const float* __restrict__ pair_w,
    float* __restrict__ y)
{
  __shared__ __hip_bfloat16 sA[128 * 32], sB[128 * 32];
  const int n_ = blockIdx.x;                    // 0..1087
  const int swz = (n_ & 7) * 136 + (n_ >> 3);
  const int tn = swz & 7;                       // H tile 0..7
  const int tm = swz >> 3;                      // row tile 0..135
  const int e  = tile_expert[tm];
  const int tid = threadIdx.x;

  const __hip_bfloat16* A = h   + (size_t)tm * 128 * F_DIM;
  const __hip_bfloat16* B = w2b + (size_t)e * H_DIM * F_DIM + (size_t)tn * 128 * F_DIM;

  const int r     = tid >> 2;
  const int s_src = (tid & 3) ^ ((r >> 1) & 3);
  const int kc    = s_src * 8;
  const int lo    = tid * 8;

  f32x4 acc[4][4] = {};
  const int wv = tid >> 6, lane = tid & 63;
  const int wr = wv >> 1, wc = wv & 1;
  const int l16 = lane & 15, lk = lane >> 4;
  const int rdk = (lk * 8) ^ (((l16 >> 1) & 3) * 8);

  for (int kt = 0; kt < F_DIM / 32; ++kt) {
    __syncthreads();
    const int gk = kt * 32 + kc;
    gload_lds16(A + (size_t)r * F_DIM + gk,          &sA[lo]);
    gload_lds16(A + (size_t)(r + 64) * F_DIM + gk,   &sA[2048 + lo]);
    gload_lds16(B + (size_t)r * F_DIM + gk,          &sB[lo]);
    gload_lds16(B + (size_t)(r + 64) * F_DIM + gk,   &sB[2048 + lo]);
    __syncthreads();

    bf16x8 af[4], bf[4];
#pragma unroll
    for (int m = 0; m < 4; ++m)
      af[m] = *reinterpret_cast<const bf16x8*>(&sA[(wr * 64 + m * 16 + l16) * 32 + rdk]);
#pragma unroll
    for (int n = 0; n < 4; ++n)
      bf[n] = *reinterpret_cast<const bf16x8*>(&sB[(wc * 64 + n * 16 + l16) * 32 + rdk]);
#pragma unroll
    for (int m = 0; m < 4; ++m)
#pragma unroll
      for (int n = 0; n < 4; ++n)
        acc[m][n] = __builtin_amdgcn_mfma_f32_16x16x32_bf16(af[m], bf[n], acc[m][n], 0, 0, 0);
  }

#pragma unroll
  for (int m = 0; m < 4; ++m)
#pragma unroll
    for (int j = 0; j < 4; ++j) {
      int rowg = tm * 128 + wr * 64 + m * 16 + lk * 4 + j;   // slot index
      float w = pair_w[rowg];                                // 0 for pad rows
      float* op = y + (size_t)rowg * H_DIM + tn * 128 + wc * 64;
#pragma unroll
      for (int n = 0; n < 4; ++n)
        op[n * 16 + l16] = w * acc[m][n][j];
    }
}

// ---------------- combine: out[t] = y[p0] + y[p1] ---------------------------
__global__ __launch_bounds__(256) void combine_kernel(
    const float* __restrict__ y, const int2* __restrict__ inv,
    float* __restrict__ out)
{
  int idx = blockIdx.x * 256 + threadIdx.x;   // T*H/4 threads, 1 token/block
  int t  = idx >> 8;
  int c  = (idx & 255) << 2;
  int2 p = inv[t];
  float4 a = *reinterpret_cast<const float4*>(y + (size_t)p.x * H_DIM + c);
  float4 b = *reinterpret_cast<const float4*>(y + (size_t)p.y * H_DIM + c);
  float4 o; o.x = a.x + b.x; o.y = a.y + b.y; o.z = a.z + b.z; o.w = a.w + b.w;
  *reinterpret_cast<float4*>(out + (size_t)t * H_DIM + c) = o;
}

// ---------------- workspace layout ------------------------------------------
#define WS_COUNTS   0
#define WS_CURSOR   32
#define WS_OFFS     64
#define WS_TILEEXP  128
#define WS_TK       1024
#define WS_PAIRTOK  132096
#define WS_PAIRW    201728
#define WS_ZERO_BYTES 271360            // counts..pair_w must be zeroed per call
#define WS_INV      271360              // int2[8192] = 64 KiB (fully written)
#define WS_XG       336896ll
#define WS_W1       (WS_XG + 35651584ll)
#define WS_W3       (WS_W1 + 67108864ll)
#define WS_W2       (WS_W3 + 67108864ll)
#define WS_H        (WS_W2 + 67108864ll)
// y (CAP*1024 fp32 = 71.3 MB) aliases xg+w1b: both dead once gemm1 finishes,
// and both are rewritten by gather/convert on every call before gemm1 runs.
#define WS_Y        WS_XG

extern "C" void kernel_launch(void* const* d_in, const int* in_sizes, int n_in,
                              void* d_out, int out_size, void* d_ws, size_t ws_size,
                              hipStream_t stream) {
  const float* x  = (const float*)d_in[0];
  const float* gw = (const float*)d_in[1];
  const float* w1 = (const float*)d_in[2];
  const float* w3 = (const float*)d_in[3];
  const float* w2 = (const float*)d_in[4];
  float* out    = (float*)d_out;
  float* logits = out + (size_t)T_TOK * H_DIM;

  char* ws = (char*)d_ws;
  int*   counts   = (int*)(ws + WS_COUNTS);
  int*   cursor   = (int*)(ws + WS_CURSOR);
  int*   offs     = (int*)(ws + WS_OFFS);
  int*   tile_exp = (int*)(ws + WS_TILEEXP);
  TK*    tk       = (TK*)(ws + WS_TK);
  int*   pair_tok = (int*)(ws + WS_PAIRTOK);
  float* pair_w   = (float*)(ws + WS_PAIRW);
  int2*  inv      = (int2*)(ws + WS_INV);
  __hip_bfloat16* xg  = (__hip_bfloat16*)(ws + WS_XG);
  __hip_bfloat16* w1b = (__hip_bfloat16*)(ws + WS_W1);
  __hip_bfloat16* w3b = (__hip_bfloat16*)(ws + WS_W3);
  __hip_bfloat16* w2b = (__hip_bfloat16*)(ws + WS_W2);
  __hip_bfloat16* hbuf = (__hip_bfloat16*)(ws + WS_H);
  float* ybuf = (float*)(ws + WS_Y);

  hipMemsetAsync(d_ws, 0, WS_ZERO_BYTES, stream);

  const long long nW = (long long)NEXP * F_DIM * H_DIM;   // 33,554,432
  convert_kernel<<<16384, 256, 0, stream>>>(w1, w1b, nW);
  convert_kernel<<<16384, 256, 0, stream>>>(w3, w3b, nW);
  convert_kernel<<<16384, 256, 0, stream>>>(w2, w2b, nW);

  router_kernel<<<T_TOK / 4, 256, 0, stream>>>(x, gw, logits, counts, tk);
  scan_kernel<<<1, 256, 0, stream>>>(counts, offs, cursor, tile_exp);
  scatter_kernel<<<T_TOK / 256, 256, 0, stream>>>(tk, cursor, pair_tok, pair_w, inv);
  gather_kernel<<<(CAP * 128) / 256, 256, 0, stream>>>(x, pair_tok, xg);

  gemm1_kernel<<<CAP_TILES * (F_DIM / 128), 256, 0, stream>>>(
      xg, w1b, w3b, tile_exp, hbuf);
  gemm2_kernel<<<CAP_TILES * (H_DIM / 128), 256, 0, stream>>>(
      hbuf, w2b, tile_exp, pair_w, ybuf);
  combine_kernel<<<(T_TOK * H_DIM / 4) / 256, 256, 0, stream>>>(ybuf, inv, out);
}